// Round 1
// baseline (442.792 us; speedup 1.0000x reference)
//
#include <hip/hip_runtime.h>

// Problem constants (B=8, T=2048, C=64, H=4, d=16)
constexpr int Bn = 8, Tn = 2048, Cn = 64, Hn = 4, Dn = 16;

// ---------------------------------------------------------------------------
// Kernel A: LayerNorm1 + QKV projection.
// One wave per row (B*T rows). lane = channel. Writes Q,K,V as [b,h,t,d].
// ---------------------------------------------------------------------------
__global__ __launch_bounds__(256) void k_ln_qkv(
    const float* __restrict__ x,
    const float* __restrict__ Wq, const float* __restrict__ Wk, const float* __restrict__ Wv,
    const float* __restrict__ g1, const float* __restrict__ b1,
    float* __restrict__ Q, float* __restrict__ K, float* __restrict__ V)
{
    const int wave = threadIdx.x >> 6, lane = threadIdx.x & 63;
    const int row  = blockIdx.x * 4 + wave;          // < 16384

    float xv = x[(size_t)row * 64 + lane];
    float s = xv, sq = xv * xv;
    #pragma unroll
    for (int off = 32; off; off >>= 1) {
        s  += __shfl_xor(s,  off);
        sq += __shfl_xor(sq, off);
    }
    const float mu  = s * (1.f / 64.f);
    const float var = sq * (1.f / 64.f) - mu * mu;
    const float rs  = rsqrtf(var + 1e-5f);
    const float hn  = (xv - mu) * rs * g1[lane] + b1[lane];

    __shared__ float sh[4][64];
    sh[wave][lane] = hn;
    __syncthreads();

    const int h = lane >> 4, d = lane & 15;
    const float* wq = Wq + h * (64 * 16) + d;
    const float* wk = Wk + h * (64 * 16) + d;
    const float* wv = Wv + h * (64 * 16) + d;
    float qa = 0.f, ka = 0.f, va = 0.f;
    #pragma unroll
    for (int c = 0; c < 64; ++c) {
        const float hc = sh[wave][c];
        qa = fmaf(hc, wq[c * 16], qa);
        ka = fmaf(hc, wk[c * 16], ka);
        va = fmaf(hc, wv[c * 16], va);
    }
    const int b = row >> 11, t = row & 2047;
    const size_t o = ((size_t)(b * 4 + h) * Tn + t) * 16 + d;
    Q[o] = qa; K[o] = ka; V[o] = va;
}

// ---------------------------------------------------------------------------
// Kernel B: causal flash attention, fp32 vector.
// Wave = 32 queries x 2 key-partitions (lane = ql + 32*part).
// Each wave handles query-sub-blocks {63-i, i} -> uniform 65 key-tiles/wave.
// K/V rows read via broadcast float4 loads (L1/L2-hot). Online softmax,
// 16-key inner tiles, cross-part merge via shfl_xor(32).
// ---------------------------------------------------------------------------
__global__ __launch_bounds__(256) void k_attn(
    const float* __restrict__ Q, const float* __restrict__ K,
    const float* __restrict__ V, float* __restrict__ O)
{
    const int wave = threadIdx.x >> 6, lane = threadIdx.x & 63;
    const int bh = blockIdx.x >> 3;                 // 0..31
    const int j  = blockIdx.x & 7;                  // 0..7
    const int i  = j * 4 + wave;                    // 0..31
    const int ql = lane & 31, part = lane >> 5;

    const float* Kb = K + (size_t)bh * Tn * 16;
    const float* Vb = V + (size_t)bh * Tn * 16;
    const int b = bh >> 2, h = bh & 3;

    for (int rep = 0; rep < 2; ++rep) {
        const int sb   = rep ? i : (63 - i);        // query sub-block (32 q's)
        const int qidx = sb * 32 + ql;

        const float4* qp = (const float4*)(Q + ((size_t)bh * Tn + qidx) * 16);
        const float4 q0 = qp[0], q1 = qp[1], q2 = qp[2], q3 = qp[3];

        float m = -1e30f, l = 0.f;
        float o[16];
        #pragma unroll
        for (int z = 0; z < 16; ++z) o[z] = 0.f;

        const int nt = sb + 1;                      // 16-key tiles per part
        for (int u = 0; u < nt; ++u) {
            const int kbase = (2 * u + part) * 16;
            float s[16];
            #pragma unroll
            for (int kk = 0; kk < 16; ++kk) {
                const int kg = kbase + kk;
                const float4* kp = (const float4*)(Kb + (size_t)kg * 16);
                const float4 k0 = kp[0], k1 = kp[1], k2 = kp[2], k3 = kp[3];
                float p0 = q0.x * k0.x, p1 = q0.y * k0.y, p2 = q0.z * k0.z, p3 = q0.w * k0.w;
                p0 = fmaf(q1.x, k1.x, p0); p1 = fmaf(q1.y, k1.y, p1);
                p2 = fmaf(q1.z, k1.z, p2); p3 = fmaf(q1.w, k1.w, p3);
                p0 = fmaf(q2.x, k2.x, p0); p1 = fmaf(q2.y, k2.y, p1);
                p2 = fmaf(q2.z, k2.z, p2); p3 = fmaf(q2.w, k2.w, p3);
                p0 = fmaf(q3.x, k3.x, p0); p1 = fmaf(q3.y, k3.y, p1);
                p2 = fmaf(q3.z, k3.z, p2); p3 = fmaf(q3.w, k3.w, p3);
                const float dv = (p0 + p1) + (p2 + p3);
                s[kk] = (kg <= qidx) ? dv * 0.25f : -1e30f;
            }
            float tm = s[0];
            #pragma unroll
            for (int kk = 1; kk < 16; ++kk) tm = fmaxf(tm, s[kk]);
            const float mnew = fmaxf(m, tm);
            if (mnew > -1e29f) {                    // skip fully-masked tile
                const float corr = __expf(m - mnew);
                l *= corr;
                #pragma unroll
                for (int z = 0; z < 16; ++z) o[z] *= corr;
                #pragma unroll
                for (int kk = 0; kk < 16; ++kk) {
                    const float p = __expf(s[kk] - mnew);
                    l += p;
                    const float4* vp = (const float4*)(Vb + (size_t)(kbase + kk) * 16);
                    const float4 v0 = vp[0], v1 = vp[1], v2 = vp[2], v3 = vp[3];
                    o[0]  = fmaf(p, v0.x, o[0]);  o[1]  = fmaf(p, v0.y, o[1]);
                    o[2]  = fmaf(p, v0.z, o[2]);  o[3]  = fmaf(p, v0.w, o[3]);
                    o[4]  = fmaf(p, v1.x, o[4]);  o[5]  = fmaf(p, v1.y, o[5]);
                    o[6]  = fmaf(p, v1.z, o[6]);  o[7]  = fmaf(p, v1.w, o[7]);
                    o[8]  = fmaf(p, v2.x, o[8]);  o[9]  = fmaf(p, v2.y, o[9]);
                    o[10] = fmaf(p, v2.z, o[10]); o[11] = fmaf(p, v2.w, o[11]);
                    o[12] = fmaf(p, v3.x, o[12]); o[13] = fmaf(p, v3.y, o[13]);
                    o[14] = fmaf(p, v3.z, o[14]); o[15] = fmaf(p, v3.w, o[15]);
                }
                m = mnew;
            }
        }

        // merge the two key-partitions (lanes l <-> l+32)
        const float mo  = __shfl_xor(m, 32);
        const float lo_ = __shfl_xor(l, 32);
        const float mn  = fmaxf(m, mo);
        const float c1  = __expf(m - mn), c2 = __expf(mo - mn);
        const float lm  = fmaf(l, c1, lo_ * c2);
        const float inv = 1.f / lm;
        float r[16];
        #pragma unroll
        for (int z = 0; z < 16; ++z) {
            const float oz = __shfl_xor(o[z], 32);
            r[z] = fmaf(o[z], c1, oz * c2) * inv;
        }
        if (part == 0) {
            float4* op = (float4*)(O + ((size_t)b * Tn + qidx) * 64 + h * 16);
            op[0] = make_float4(r[0],  r[1],  r[2],  r[3]);
            op[1] = make_float4(r[4],  r[5],  r[6],  r[7]);
            op[2] = make_float4(r[8],  r[9],  r[10], r[11]);
            op[3] = make_float4(r[12], r[13], r[14], r[15]);
        }
    }
}

// ---------------------------------------------------------------------------
// Kernel C: out-proj + residual + LN2 + MLP + residual -> d_out.
// One wave per row; hidden (256) staged in LDS.
// ---------------------------------------------------------------------------
__global__ __launch_bounds__(256) void k_proj_mlp(
    const float* __restrict__ x,  const float* __restrict__ AO,
    const float* __restrict__ Wo, const float* __restrict__ bo,
    const float* __restrict__ g2, const float* __restrict__ b2v,
    const float* __restrict__ W1, const float* __restrict__ bias1,
    const float* __restrict__ W2, const float* __restrict__ bias2,
    float* __restrict__ out)
{
    const int wave = threadIdx.x >> 6, lane = threadIdx.x & 63;
    const int row  = blockIdx.x * 4 + wave;

    // y = x + attn_out @ Wo + bo
    const float4* ar = (const float4*)(AO + (size_t)row * 64);
    float acc = bo[lane];
    #pragma unroll
    for (int jj = 0; jj < 16; ++jj) {
        const float4 a4 = ar[jj];
        const int jr = jj * 4;
        acc = fmaf(a4.x, Wo[(jr + 0) * 64 + lane], acc);
        acc = fmaf(a4.y, Wo[(jr + 1) * 64 + lane], acc);
        acc = fmaf(a4.z, Wo[(jr + 2) * 64 + lane], acc);
        acc = fmaf(a4.w, Wo[(jr + 3) * 64 + lane], acc);
    }
    const float y = x[(size_t)row * 64 + lane] + acc;

    // LN2
    float s = y, sq = y * y;
    #pragma unroll
    for (int off = 32; off; off >>= 1) {
        s  += __shfl_xor(s,  off);
        sq += __shfl_xor(sq, off);
    }
    const float mu  = s * (1.f / 64.f);
    const float var = sq * (1.f / 64.f) - mu * mu;
    const float rs  = rsqrtf(var + 1e-5f);
    const float hn  = (y - mu) * rs * g2[lane] + b2v[lane];

    __shared__ float shn[4][64];
    __shared__ float shid[4][256];
    shn[wave][lane] = hn;
    __syncthreads();

    // fc1 (64 -> 256), each lane computes 4 hidden units
    float h0 = bias1[lane], h1 = bias1[lane + 64], h2 = bias1[lane + 128], h3 = bias1[lane + 192];
    #pragma unroll
    for (int cc = 0; cc < 64; ++cc) {
        const float hc = shn[wave][cc];
        const float* w = W1 + cc * 256 + lane;
        h0 = fmaf(hc, w[0],   h0);
        h1 = fmaf(hc, w[64],  h1);
        h2 = fmaf(hc, w[128], h2);
        h3 = fmaf(hc, w[192], h3);
    }
    shid[wave][lane]       = fmaxf(h0, 0.f);
    shid[wave][lane + 64]  = fmaxf(h1, 0.f);
    shid[wave][lane + 128] = fmaxf(h2, 0.f);
    shid[wave][lane + 192] = fmaxf(h3, 0.f);
    __syncthreads();

    // fc2 (256 -> 64) + residual
    float f = bias2[lane];
    #pragma unroll 16
    for (int kk = 0; kk < 256; ++kk) {
        f = fmaf(shid[wave][kk], W2[kk * 64 + lane], f);
    }
    out[(size_t)row * 64 + lane] = y + f;
}

// ---------------------------------------------------------------------------
extern "C" void kernel_launch(void* const* d_in, const int* in_sizes, int n_in,
                              void* d_out, int out_size, void* d_ws, size_t ws_size,
                              hipStream_t stream)
{
    const float* x     = (const float*)d_in[0];
    const float* Wq    = (const float*)d_in[1];
    const float* Wk    = (const float*)d_in[2];
    const float* Wv    = (const float*)d_in[3];
    const float* Wo    = (const float*)d_in[4];
    const float* bo    = (const float*)d_in[5];
    const float* W1    = (const float*)d_in[6];
    const float* bias1 = (const float*)d_in[7];
    const float* W2    = (const float*)d_in[8];
    const float* bias2 = (const float*)d_in[9];
    const float* g1    = (const float*)d_in[10];
    const float* be1   = (const float*)d_in[11];
    const float* g2    = (const float*)d_in[12];
    const float* be2   = (const float*)d_in[13];

    float* ws = (float*)d_ws;
    const size_t sz = (size_t)Bn * Hn * Tn * Dn;   // 1,048,576 floats each
    float* Q  = ws;
    float* K  = ws + sz;
    float* V  = ws + 2 * sz;
    float* AO = ws + 3 * sz;                       // attention out, (B,T,C)

    k_ln_qkv<<<dim3((Bn * Tn) / 4), dim3(256), 0, stream>>>(x, Wq, Wk, Wv, g1, be1, Q, K, V);
    k_attn<<<dim3(32 * 8), dim3(256), 0, stream>>>(Q, K, V, AO);
    k_proj_mlp<<<dim3((Bn * Tn) / 4), dim3(256), 0, stream>>>(
        x, AO, Wo, bo, g2, be2, W1, bias1, W2, bias2, (float*)d_out);
}

// Round 3
// 141.532 us; speedup vs baseline: 3.1286x; 3.1286x over previous
//
#include <hip/hip_runtime.h>

// Problem constants (B=8, T=2048, C=64, H=4, d=16)
constexpr int Bn = 8, Tn = 2048;

typedef __bf16 bf16x8 __attribute__((ext_vector_type(8)));
typedef float  f32x16 __attribute__((ext_vector_type(16)));

__device__ __forceinline__ unsigned short f2bf(float f) {
    __bf16 h = (__bf16)f;
    return __builtin_bit_cast(unsigned short, h);
}

// ---------------------------------------------------------------------------
// Kernel A: LayerNorm1 + QKV projection.
// One wave per row. Writes bf16 Qb (pre-scaled by 1/sqrt(d)=0.25, exact),
// bf16 Kb as [bh][t][16], and bf16 V TRANSPOSED as VT[bh][d=16][t].
// ---------------------------------------------------------------------------
__global__ __launch_bounds__(256) void k_ln_qkv(
    const float* __restrict__ x,
    const float* __restrict__ Wq, const float* __restrict__ Wk, const float* __restrict__ Wv,
    const float* __restrict__ g1, const float* __restrict__ b1,
    unsigned short* __restrict__ Qb, unsigned short* __restrict__ Kb,
    unsigned short* __restrict__ VT)
{
    const int wave = threadIdx.x >> 6, lane = threadIdx.x & 63;
    const int row  = blockIdx.x * 4 + wave;          // < 16384

    float xv = x[(size_t)row * 64 + lane];
    float s = xv, sq = xv * xv;
    #pragma unroll
    for (int off = 32; off; off >>= 1) {
        s  += __shfl_xor(s,  off);
        sq += __shfl_xor(sq, off);
    }
    const float mu  = s * (1.f / 64.f);
    const float var = sq * (1.f / 64.f) - mu * mu;
    const float rs  = rsqrtf(var + 1e-5f);
    const float hn  = (xv - mu) * rs * g1[lane] + b1[lane];

    __shared__ float sh[4][64];
    sh[wave][lane] = hn;
    __syncthreads();

    const int h = lane >> 4, d = lane & 15;
    const float* wq = Wq + h * (64 * 16) + d;
    const float* wk = Wk + h * (64 * 16) + d;
    const float* wv = Wv + h * (64 * 16) + d;
    float qa = 0.f, ka = 0.f, va = 0.f;
    #pragma unroll
    for (int c = 0; c < 64; ++c) {
        const float hc = sh[wave][c];
        qa = fmaf(hc, wq[c * 16], qa);
        ka = fmaf(hc, wk[c * 16], ka);
        va = fmaf(hc, wv[c * 16], va);
    }
    const int b = row >> 11, t = row & 2047;
    const int bh = b * 4 + h;
    Qb[((size_t)bh * Tn + t) * 16 + d] = f2bf(qa * 0.25f);
    Kb[((size_t)bh * Tn + t) * 16 + d] = f2bf(ka);
    VT[((size_t)bh * 16 + d) * Tn + t] = f2bf(va);
}

// ---------------------------------------------------------------------------
// Kernel B: causal flash attention via mfma_f32_32x32x16_bf16.
//
// Swapped QK^T: S^T[key][q] = mfma(A=K, B=Q^T). Both fragments are loaded
// with the SAME (lane-half, element)->d map (contiguous d = 8*hi + e), which
// makes the dot product correct regardless of the hardware's physical k-slot
// order. C/D layout (HW-verified): col = lane&31 = q,
// row = (r&3) + 8*(r>>2) + 4*hi = key ("crow order").
//
// PV: O^T[d][q] = mfma(A=V^T, B=P^T). Correct iff V^T's key map equals P's
// placement map. We use contiguous key = kbase + 16*t + 8*hi + e for both:
// V^T via one bf16x8 load, P rearranged from crow order into contiguous
// order with an 8x shfl_xor(32) half-exchange (the T12 structure).
//
// Softmax state m is cross-half synced each tile; l is cross-half summed at
// the end. Sentinel -30000 (exp underflows to exact 0; no huge magnitudes).
// Work: wave = (bh, qt-pair {qtA, 63-qtA}, key-half w). 2048 waves total,
// key-halves merged through LDS after a barrier.
// ---------------------------------------------------------------------------
__global__ __launch_bounds__(256) void k_attn(
    const unsigned short* __restrict__ Qb, const unsigned short* __restrict__ Kb,
    const unsigned short* __restrict__ VT, float* __restrict__ AO)
{
    const int wave = threadIdx.x >> 6, lane = threadIdx.x & 63;
    const int bh = blockIdx.x >> 4;                  // 0..31
    const int pg = blockIdx.x & 15;                  // 0..15
    const int sub = wave >> 1, w = wave & 1;         // sub: qt-pair, w: key half
    const int hi = lane >> 5, qcol = lane & 31;
    const int b = bh >> 2, h = bh & 3;

    const unsigned short* Qbh = Qb + (size_t)bh * (Tn * 16);
    const unsigned short* Kbh = Kb + (size_t)bh * (Tn * 16);
    const unsigned short* Vbh = VT + (size_t)bh * (16 * Tn);

    __shared__ float red[4][2][64][12];              // m, l, o[8], pad

    const int qtA = 2 * pg + sub;                    // 0..31

    for (int rep = 0; rep < 2; ++rep) {
        const int qt = rep ? (63 - qtA) : qtA;
        const int qg = qt * 32 + qcol;

        const bf16x8 qf = *(const bf16x8*)(Qbh + (size_t)qg * 16 + 8 * hi);

        float m = -30000.f, l = 0.f;
        f32x16 oacc = {};

        for (int kt = w; kt <= qt; kt += 2) {
            const int kbase = kt * 32;
            const bf16x8 kf = *(const bf16x8*)(Kbh + (size_t)(kbase + qcol) * 16 + 8 * hi);
            f32x16 z = {};
            f32x16 st = __builtin_amdgcn_mfma_f32_32x32x16_bf16(kf, qf, z, 0, 0, 0);

            float sv[16];
            #pragma unroll
            for (int r = 0; r < 16; ++r) sv[r] = st[r];
            if (kt == qt) {                          // diagonal: causal mask
                #pragma unroll
                for (int r = 0; r < 16; ++r) {
                    const int kr = (r & 3) + 8 * (r >> 2) + 4 * hi;
                    if (kr > qcol) sv[r] = -30000.f;
                }
            }

            float tm = sv[0];
            #pragma unroll
            for (int r = 1; r < 16; ++r) tm = fmaxf(tm, sv[r]);
            tm = fmaxf(tm, __shfl_xor(tm, 32));      // cross-half max (same q)
            const float mnew = fmaxf(m, tm);
            const float corr = __expf(m - mnew);
            m = mnew;
            l *= corr;
            #pragma unroll
            for (int r = 0; r < 8; ++r) oacc[r] *= corr;   // valid d rows

            float p[16];
            float ps = 0.f;
            #pragma unroll
            for (int r = 0; r < 16; ++r) { p[r] = __expf(sv[r] - mnew); ps += p[r]; }
            l += ps;

            // crow(r,hi) = (r&3)+8*(r>>2)+4*hi. B operand needs contiguous
            // key = 16*t + 8*hi + e. Exchange the mismatched quads across
            // lane<32/lane>=32 (own: e<4 @hi=0 and e>=4 @hi=1).
            const float x0 = hi ? p[0]  : p[4];
            const float x1 = hi ? p[1]  : p[5];
            const float x2 = hi ? p[2]  : p[6];
            const float x3 = hi ? p[3]  : p[7];
            const float x4 = hi ? p[8]  : p[12];
            const float x5 = hi ? p[9]  : p[13];
            const float x6 = hi ? p[10] : p[14];
            const float x7 = hi ? p[11] : p[15];
            const float r0 = __shfl_xor(x0, 32), r1 = __shfl_xor(x1, 32);
            const float r2 = __shfl_xor(x2, 32), r3 = __shfl_xor(x3, 32);
            const float r4 = __shfl_xor(x4, 32), r5 = __shfl_xor(x5, 32);
            const float r6 = __shfl_xor(x6, 32), r7 = __shfl_xor(x7, 32);

            bf16x8 pa0, pa1;
            pa0[0] = (__bf16)(hi ? r0 : p[0]);
            pa0[1] = (__bf16)(hi ? r1 : p[1]);
            pa0[2] = (__bf16)(hi ? r2 : p[2]);
            pa0[3] = (__bf16)(hi ? r3 : p[3]);
            pa0[4] = (__bf16)(hi ? p[4] : r0);
            pa0[5] = (__bf16)(hi ? p[5] : r1);
            pa0[6] = (__bf16)(hi ? p[6] : r2);
            pa0[7] = (__bf16)(hi ? p[7] : r3);
            pa1[0] = (__bf16)(hi ? r4 : p[8]);
            pa1[1] = (__bf16)(hi ? r5 : p[9]);
            pa1[2] = (__bf16)(hi ? r6 : p[10]);
            pa1[3] = (__bf16)(hi ? r7 : p[11]);
            pa1[4] = (__bf16)(hi ? p[12] : r4);
            pa1[5] = (__bf16)(hi ? p[13] : r5);
            pa1[6] = (__bf16)(hi ? p[14] : r6);
            pa1[7] = (__bf16)(hi ? p[15] : r7);

            const unsigned short* vrow = Vbh + (size_t)(lane & 15) * Tn + kbase + 8 * hi;
            const bf16x8 vf0 = *(const bf16x8*)(vrow);        // keys kbase+8hi+e
            const bf16x8 vf1 = *(const bf16x8*)(vrow + 16);   // keys kbase+16+8hi+e

            oacc = __builtin_amdgcn_mfma_f32_32x32x16_bf16(vf0, pa0, oacc, 0, 0, 0);
            oacc = __builtin_amdgcn_mfma_f32_32x32x16_bf16(vf1, pa1, oacc, 0, 0, 0);
        }

        l += __shfl_xor(l, 32);                      // total over both halves

        float* sp = &red[wave][rep][lane][0];
        sp[0] = m; sp[1] = l;
        #pragma unroll
        for (int r = 0; r < 8; ++r) sp[2 + r] = oacc[r];
    }
    __syncthreads();

    // merge key-halves: waves (2*subm) and (2*subm+1) share the qt pair.
    const int r_m = wave & 1, subm = wave >> 1;
    const float* pa = &red[2 * subm][r_m][lane][0];
    const float* pb = &red[2 * subm + 1][r_m][lane][0];
    const float ma = pa[0], la = pa[1], mb = pb[0], lb = pb[1];
    const float mm = fmaxf(ma, mb);
    const float ca = __expf(ma - mm), cb = __expf(mb - mm);
    const float lt = fmaf(la, ca, lb * cb);
    const float inv = 1.f / lt;

    const int qt_out = r_m ? (63 - (2 * pg + subm)) : (2 * pg + subm);
    const int qg2 = qt_out * 32 + qcol;

    float o[8];
    #pragma unroll
    for (int r = 0; r < 8; ++r) o[r] = fmaf(pa[2 + r], ca, pb[2 + r] * cb) * inv;

    // reg r -> d = (r&3) + 8*(r>>2) + 4*hi : two contiguous float4 groups
    float* dst = AO + ((size_t)b * Tn + qg2) * 64 + h * 16;
    *(float4*)(dst + 4 * hi)     = make_float4(o[0], o[1], o[2], o[3]);
    *(float4*)(dst + 8 + 4 * hi) = make_float4(o[4], o[5], o[6], o[7]);
}

// ---------------------------------------------------------------------------
// Kernel C: out-proj + residual + LN2 + MLP + residual -> d_out.
// ---------------------------------------------------------------------------
__global__ __launch_bounds__(256) void k_proj_mlp(
    const float* __restrict__ x,  const float* __restrict__ AO,
    const float* __restrict__ Wo, const float* __restrict__ bo,
    const float* __restrict__ g2, const float* __restrict__ b2v,
    const float* __restrict__ W1, const float* __restrict__ bias1,
    const float* __restrict__ W2, const float* __restrict__ bias2,
    float* __restrict__ out)
{
    const int wave = threadIdx.x >> 6, lane = threadIdx.x & 63;
    const int row  = blockIdx.x * 4 + wave;

    const float4* ar = (const float4*)(AO + (size_t)row * 64);
    float acc = bo[lane];
    #pragma unroll
    for (int jj = 0; jj < 16; ++jj) {
        const float4 a4 = ar[jj];
        const int jr = jj * 4;
        acc = fmaf(a4.x, Wo[(jr + 0) * 64 + lane], acc);
        acc = fmaf(a4.y, Wo[(jr + 1) * 64 + lane], acc);
        acc = fmaf(a4.z, Wo[(jr + 2) * 64 + lane], acc);
        acc = fmaf(a4.w, Wo[(jr + 3) * 64 + lane], acc);
    }
    const float y = x[(size_t)row * 64 + lane] + acc;

    float s = y, sq = y * y;
    #pragma unroll
    for (int off = 32; off; off >>= 1) {
        s  += __shfl_xor(s,  off);
        sq += __shfl_xor(sq, off);
    }
    const float mu  = s * (1.f / 64.f);
    const float var = sq * (1.f / 64.f) - mu * mu;
    const float rs  = rsqrtf(var + 1e-5f);
    const float hn  = (y - mu) * rs * g2[lane] + b2v[lane];

    __shared__ float shn[4][64];
    __shared__ float shid[4][256];
    shn[wave][lane] = hn;
    __syncthreads();

    float h0 = bias1[lane], h1 = bias1[lane + 64], h2 = bias1[lane + 128], h3 = bias1[lane + 192];
    #pragma unroll
    for (int cc = 0; cc < 64; ++cc) {
        const float hc = shn[wave][cc];
        const float* wgt = W1 + cc * 256 + lane;
        h0 = fmaf(hc, wgt[0],   h0);
        h1 = fmaf(hc, wgt[64],  h1);
        h2 = fmaf(hc, wgt[128], h2);
        h3 = fmaf(hc, wgt[192], h3);
    }
    shid[wave][lane]       = fmaxf(h0, 0.f);
    shid[wave][lane + 64]  = fmaxf(h1, 0.f);
    shid[wave][lane + 128] = fmaxf(h2, 0.f);
    shid[wave][lane + 192] = fmaxf(h3, 0.f);
    __syncthreads();

    float f = bias2[lane];
    #pragma unroll 16
    for (int kk = 0; kk < 256; ++kk) {
        f = fmaf(shid[wave][kk], W2[kk * 64 + lane], f);
    }
    out[(size_t)row * 64 + lane] = y + f;
}

// ---------------------------------------------------------------------------
extern "C" void kernel_launch(void* const* d_in, const int* in_sizes, int n_in,
                              void* d_out, int out_size, void* d_ws, size_t ws_size,
                              hipStream_t stream)
{
    const float* x     = (const float*)d_in[0];
    const float* Wq    = (const float*)d_in[1];
    const float* Wk    = (const float*)d_in[2];
    const float* Wv    = (const float*)d_in[3];
    const float* Wo    = (const float*)d_in[4];
    const float* bo    = (const float*)d_in[5];
    const float* W1    = (const float*)d_in[6];
    const float* bias1 = (const float*)d_in[7];
    const float* W2    = (const float*)d_in[8];
    const float* bias2 = (const float*)d_in[9];
    const float* g1    = (const float*)d_in[10];
    const float* be1   = (const float*)d_in[11];
    const float* g2    = (const float*)d_in[12];
    const float* be2   = (const float*)d_in[13];

    const size_t nBF = (size_t)32 * Tn * 16;         // 1M elements per buffer
    unsigned short* Qb = (unsigned short*)d_ws;
    unsigned short* Kb = Qb + nBF;
    unsigned short* VT = Kb + nBF;
    float* AO = (float*)(VT + nBF);                  // 4 MB, (B,T,C) f32

    k_ln_qkv<<<dim3((Bn * Tn) / 4), dim3(256), 0, stream>>>(x, Wq, Wk, Wv, g1, be1, Qb, Kb, VT);
    k_attn<<<dim3(32 * 16), dim3(256), 0, stream>>>(Qb, Kb, VT, AO);
    k_proj_mlp<<<dim3((Bn * Tn) / 4), dim3(256), 0, stream>>>(
        x, AO, Wo, bo, g2, be2, W1, bias1, W2, bias2, (float*)d_out);
}

// Round 4
// 139.213 us; speedup vs baseline: 3.1807x; 1.0167x over previous
//
#include <hip/hip_runtime.h>

// Problem constants (B=8, T=2048, C=64, H=4, d=16)
constexpr int Bn = 8, Tn = 2048;

typedef __bf16 bf16x8 __attribute__((ext_vector_type(8)));
typedef float  f32x16 __attribute__((ext_vector_type(16)));

__device__ __forceinline__ unsigned short f2bf(float f) {
    __bf16 h = (__bf16)f;
    return __builtin_bit_cast(unsigned short, h);
}

// ---------------------------------------------------------------------------
// Kernel A: LayerNorm1 + QKV projection.
// One wave per row. Writes bf16 Qb (pre-scaled by 1/sqrt(d)=0.25, exact),
// bf16 Kb as [bh][t][16], and bf16 V TRANSPOSED as VT[bh][d=16][t].
// ---------------------------------------------------------------------------
__global__ __launch_bounds__(256) void k_ln_qkv(
    const float* __restrict__ x,
    const float* __restrict__ Wq, const float* __restrict__ Wk, const float* __restrict__ Wv,
    const float* __restrict__ g1, const float* __restrict__ b1,
    unsigned short* __restrict__ Qb, unsigned short* __restrict__ Kb,
    unsigned short* __restrict__ VT)
{
    const int wave = threadIdx.x >> 6, lane = threadIdx.x & 63;
    const int row  = blockIdx.x * 4 + wave;          // < 16384

    float xv = x[(size_t)row * 64 + lane];
    float s = xv, sq = xv * xv;
    #pragma unroll
    for (int off = 32; off; off >>= 1) {
        s  += __shfl_xor(s,  off);
        sq += __shfl_xor(sq, off);
    }
    const float mu  = s * (1.f / 64.f);
    const float var = sq * (1.f / 64.f) - mu * mu;
    const float rs  = rsqrtf(var + 1e-5f);
    const float hn  = (xv - mu) * rs * g1[lane] + b1[lane];

    __shared__ float sh[4][64];
    sh[wave][lane] = hn;
    __syncthreads();

    const int h = lane >> 4, d = lane & 15;
    const float* wq = Wq + h * (64 * 16) + d;
    const float* wk = Wk + h * (64 * 16) + d;
    const float* wv = Wv + h * (64 * 16) + d;
    // 2 independent chains per output (split c range) for ILP
    float qa = 0.f, ka = 0.f, va = 0.f, qb2 = 0.f, kb2 = 0.f, vb2 = 0.f;
    #pragma unroll
    for (int c = 0; c < 32; ++c) {
        const float ha = sh[wave][c], hb = sh[wave][c + 32];
        qa  = fmaf(ha, wq[c * 16], qa);
        ka  = fmaf(ha, wk[c * 16], ka);
        va  = fmaf(ha, wv[c * 16], va);
        qb2 = fmaf(hb, wq[(c + 32) * 16], qb2);
        kb2 = fmaf(hb, wk[(c + 32) * 16], kb2);
        vb2 = fmaf(hb, wv[(c + 32) * 16], vb2);
    }
    const int b = row >> 11, t = row & 2047;
    const int bh = b * 4 + h;
    Qb[((size_t)bh * Tn + t) * 16 + d] = f2bf((qa + qb2) * 0.25f);
    Kb[((size_t)bh * Tn + t) * 16 + d] = f2bf(ka + kb2);
    VT[((size_t)bh * 16 + d) * Tn + t] = f2bf(va + vb2);
}

// ---------------------------------------------------------------------------
// Kernel B: causal flash attention via mfma_f32_32x32x16_bf16.
// Swapped QK^T (S^T = mfma(K, Q)); PV via V^T with matched contiguous key
// maps; P moved from C/D "crow" order to B-operand order with 8x shfl_xor(32).
// Work: block = (bh, qtA); 4 waves = 4 key-quarters (kt ≡ w mod 4) over the
// qt-pair {qtA, 63-qtA}. 4096 waves (4/SIMD). 4-way merge through LDS.
// Defer-max: skip the rescale pass when no lane's max grew (T13).
// ---------------------------------------------------------------------------
__global__ __launch_bounds__(256) void k_attn(
    const unsigned short* __restrict__ Qb, const unsigned short* __restrict__ Kb,
    const unsigned short* __restrict__ VT, float* __restrict__ AO)
{
    const int wave = threadIdx.x >> 6, lane = threadIdx.x & 63;
    const int bh  = blockIdx.x >> 5;                 // 0..31
    const int qtA = blockIdx.x & 31;                 // 0..31
    const int w = wave;                              // key quarter
    const int hi = lane >> 5, qcol = lane & 31;
    const int b = bh >> 2, h = bh & 3;

    const unsigned short* Qbh = Qb + (size_t)bh * (Tn * 16);
    const unsigned short* Kbh = Kb + (size_t)bh * (Tn * 16);
    const unsigned short* Vbh = VT + (size_t)bh * (16 * Tn);

    __shared__ float red[4][2][64][12];              // m, l, o[8], pad

    for (int rep = 0; rep < 2; ++rep) {
        const int qt = rep ? (63 - qtA) : qtA;
        const int qg = qt * 32 + qcol;

        const bf16x8 qf = *(const bf16x8*)(Qbh + (size_t)qg * 16 + 8 * hi);

        float m = -30000.f, l = 0.f;
        f32x16 oacc = {};

        for (int kt = w; kt <= qt; kt += 4) {
            const int kbase = kt * 32;
            const bf16x8 kf = *(const bf16x8*)(Kbh + (size_t)(kbase + qcol) * 16 + 8 * hi);
            f32x16 z = {};
            f32x16 st = __builtin_amdgcn_mfma_f32_32x32x16_bf16(kf, qf, z, 0, 0, 0);

            float sv[16];
            #pragma unroll
            for (int r = 0; r < 16; ++r) sv[r] = st[r];
            if (kt == qt) {                          // diagonal: causal mask
                #pragma unroll
                for (int r = 0; r < 16; ++r) {
                    const int kr = (r & 3) + 8 * (r >> 2) + 4 * hi;
                    if (kr > qcol) sv[r] = -30000.f;
                }
            }

            float tm = sv[0];
            #pragma unroll
            for (int r = 1; r < 16; ++r) tm = fmaxf(tm, sv[r]);
            tm = fmaxf(tm, __shfl_xor(tm, 32));      // cross-half max (same q)
            const float mnew = fmaxf(m, tm);
            if (!__all(mnew <= m)) {                 // defer-max: rescale only on growth
                const float corr = __expf(m - mnew);
                m = mnew;
                l *= corr;
                #pragma unroll
                for (int r = 0; r < 8; ++r) oacc[r] *= corr;
            }

            float p[16];
            float ps = 0.f;
            #pragma unroll
            for (int r = 0; r < 16; ++r) { p[r] = __expf(sv[r] - m); ps += p[r]; }
            l += ps;

            // crow(r,hi) = (r&3)+8*(r>>2)+4*hi -> contiguous key = 16*t+8*hi+e
            const float x0 = hi ? p[0]  : p[4];
            const float x1 = hi ? p[1]  : p[5];
            const float x2 = hi ? p[2]  : p[6];
            const float x3 = hi ? p[3]  : p[7];
            const float x4 = hi ? p[8]  : p[12];
            const float x5 = hi ? p[9]  : p[13];
            const float x6 = hi ? p[10] : p[14];
            const float x7 = hi ? p[11] : p[15];
            const float r0 = __shfl_xor(x0, 32), r1 = __shfl_xor(x1, 32);
            const float r2 = __shfl_xor(x2, 32), r3 = __shfl_xor(x3, 32);
            const float r4 = __shfl_xor(x4, 32), r5 = __shfl_xor(x5, 32);
            const float r6 = __shfl_xor(x6, 32), r7 = __shfl_xor(x7, 32);

            bf16x8 pa0, pa1;
            pa0[0] = (__bf16)(hi ? r0 : p[0]);
            pa0[1] = (__bf16)(hi ? r1 : p[1]);
            pa0[2] = (__bf16)(hi ? r2 : p[2]);
            pa0[3] = (__bf16)(hi ? r3 : p[3]);
            pa0[4] = (__bf16)(hi ? p[4] : r0);
            pa0[5] = (__bf16)(hi ? p[5] : r1);
            pa0[6] = (__bf16)(hi ? p[6] : r2);
            pa0[7] = (__bf16)(hi ? p[7] : r3);
            pa1[0] = (__bf16)(hi ? r4 : p[8]);
            pa1[1] = (__bf16)(hi ? r5 : p[9]);
            pa1[2] = (__bf16)(hi ? r6 : p[10]);
            pa1[3] = (__bf16)(hi ? r7 : p[11]);
            pa1[4] = (__bf16)(hi ? p[12] : r4);
            pa1[5] = (__bf16)(hi ? p[13] : r5);
            pa1[6] = (__bf16)(hi ? p[14] : r6);
            pa1[7] = (__bf16)(hi ? p[15] : r7);

            const unsigned short* vrow = Vbh + (size_t)(lane & 15) * Tn + kbase + 8 * hi;
            const bf16x8 vf0 = *(const bf16x8*)(vrow);        // keys kbase+8hi+e
            const bf16x8 vf1 = *(const bf16x8*)(vrow + 16);   // keys kbase+16+8hi+e

            oacc = __builtin_amdgcn_mfma_f32_32x32x16_bf16(vf0, pa0, oacc, 0, 0, 0);
            oacc = __builtin_amdgcn_mfma_f32_32x32x16_bf16(vf1, pa1, oacc, 0, 0, 0);
        }

        l += __shfl_xor(l, 32);                      // total over both halves

        float* sp = &red[wave][rep][lane][0];
        sp[0] = m; sp[1] = l;
        #pragma unroll
        for (int r = 0; r < 8; ++r) sp[2 + r] = oacc[r];
    }
    __syncthreads();

    // 4-way merge: wave 0 merges rep0, wave 1 merges rep1.
    if (wave < 2) {
        const int r_m = wave;
        const float* p0 = &red[0][r_m][lane][0];
        const float* p1 = &red[1][r_m][lane][0];
        const float* p2 = &red[2][r_m][lane][0];
        const float* p3 = &red[3][r_m][lane][0];
        const float mm = fmaxf(fmaxf(p0[0], p1[0]), fmaxf(p2[0], p3[0]));
        const float c0 = __expf(p0[0] - mm), c1 = __expf(p1[0] - mm);
        const float c2 = __expf(p2[0] - mm), c3 = __expf(p3[0] - mm);
        const float lt = fmaf(p0[1], c0, fmaf(p1[1], c1, fmaf(p2[1], c2, p3[1] * c3)));
        const float inv = 1.f / lt;

        const int qt_out = r_m ? (63 - qtA) : qtA;
        const int qg2 = qt_out * 32 + qcol;

        float o[8];
        #pragma unroll
        for (int r = 0; r < 8; ++r)
            o[r] = fmaf(p0[2 + r], c0, fmaf(p1[2 + r], c1,
                   fmaf(p2[2 + r], c2, p3[2 + r] * c3))) * inv;

        // reg r -> d = (r&3) + 8*(r>>2) + 4*hi : two contiguous float4 groups
        float* dst = AO + ((size_t)b * Tn + qg2) * 64 + h * 16;
        *(float4*)(dst + 4 * hi)     = make_float4(o[0], o[1], o[2], o[3]);
        *(float4*)(dst + 8 + 4 * hi) = make_float4(o[4], o[5], o[6], o[7]);
    }
}

// ---------------------------------------------------------------------------
// Kernel C: out-proj + residual + LN2 + MLP + residual -> d_out.
// ILP-restructured: every dot product split into independent accumulator
// chains (Wo 4x16, fc1 8x32, fc2 8x32) to break fp32 FMA latency serialization.
// ---------------------------------------------------------------------------
__global__ __launch_bounds__(256) void k_proj_mlp(
    const float* __restrict__ x,  const float* __restrict__ AO,
    const float* __restrict__ Wo, const float* __restrict__ bo,
    const float* __restrict__ g2, const float* __restrict__ b2v,
    const float* __restrict__ W1, const float* __restrict__ bias1,
    const float* __restrict__ W2, const float* __restrict__ bias2,
    float* __restrict__ out)
{
    const int wave = threadIdx.x >> 6, lane = threadIdx.x & 63;
    const int row  = blockIdx.x * 4 + wave;

    // y = x + AO @ Wo + bo : 4 independent chains
    const float4* ar = (const float4*)(AO + (size_t)row * 64);
    float a0 = 0.f, a1 = 0.f, a2 = 0.f, a3 = 0.f;
    #pragma unroll
    for (int jj = 0; jj < 16; ++jj) {
        const float4 a4 = ar[jj];
        const int jr = jj * 4;
        a0 = fmaf(a4.x, Wo[(jr + 0) * 64 + lane], a0);
        a1 = fmaf(a4.y, Wo[(jr + 1) * 64 + lane], a1);
        a2 = fmaf(a4.z, Wo[(jr + 2) * 64 + lane], a2);
        a3 = fmaf(a4.w, Wo[(jr + 3) * 64 + lane], a3);
    }
    const float y = x[(size_t)row * 64 + lane] + bo[lane] + ((a0 + a1) + (a2 + a3));

    float s = y, sq = y * y;
    #pragma unroll
    for (int off = 32; off; off >>= 1) {
        s  += __shfl_xor(s,  off);
        sq += __shfl_xor(sq, off);
    }
    const float mu  = s * (1.f / 64.f);
    const float var = sq * (1.f / 64.f) - mu * mu;
    const float rs  = rsqrtf(var + 1e-5f);
    const float hn  = (y - mu) * rs * g2[lane] + b2v[lane];

    __shared__ float shn[4][64];
    __shared__ float shid[4][256];
    shn[wave][lane] = hn;
    __syncthreads();

    // fc1 (64 -> 256): 4 hidden units/lane, 2 chains each (split c range)
    float h0a = 0.f, h1a = 0.f, h2a = 0.f, h3a = 0.f;
    float h0b = 0.f, h1b = 0.f, h2b = 0.f, h3b = 0.f;
    #pragma unroll
    for (int cc = 0; cc < 32; ++cc) {
        const float ha = shn[wave][cc];
        const float hb = shn[wave][cc + 32];
        const float* wa = W1 + cc * 256 + lane;
        const float* wb = W1 + (cc + 32) * 256 + lane;
        h0a = fmaf(ha, wa[0],   h0a);  h0b = fmaf(hb, wb[0],   h0b);
        h1a = fmaf(ha, wa[64],  h1a);  h1b = fmaf(hb, wb[64],  h1b);
        h2a = fmaf(ha, wa[128], h2a);  h2b = fmaf(hb, wb[128], h2b);
        h3a = fmaf(ha, wa[192], h3a);  h3b = fmaf(hb, wb[192], h3b);
    }
    shid[wave][lane]       = fmaxf(bias1[lane]       + h0a + h0b, 0.f);
    shid[wave][lane + 64]  = fmaxf(bias1[lane + 64]  + h1a + h1b, 0.f);
    shid[wave][lane + 128] = fmaxf(bias1[lane + 128] + h2a + h2b, 0.f);
    shid[wave][lane + 192] = fmaxf(bias1[lane + 192] + h3a + h3b, 0.f);
    __syncthreads();

    // fc2 (256 -> 64) + residual : 8 independent chains of 32
    float f0 = 0.f, f1 = 0.f, f2 = 0.f, f3 = 0.f;
    float f4 = 0.f, f5 = 0.f, f6 = 0.f, f7 = 0.f;
    #pragma unroll
    for (int kk = 0; kk < 32; ++kk) {
        f0 = fmaf(shid[wave][kk],       W2[(kk)       * 64 + lane], f0);
        f1 = fmaf(shid[wave][kk + 32],  W2[(kk + 32)  * 64 + lane], f1);
        f2 = fmaf(shid[wave][kk + 64],  W2[(kk + 64)  * 64 + lane], f2);
        f3 = fmaf(shid[wave][kk + 96],  W2[(kk + 96)  * 64 + lane], f3);
        f4 = fmaf(shid[wave][kk + 128], W2[(kk + 128) * 64 + lane], f4);
        f5 = fmaf(shid[wave][kk + 160], W2[(kk + 160) * 64 + lane], f5);
        f6 = fmaf(shid[wave][kk + 192], W2[(kk + 192) * 64 + lane], f6);
        f7 = fmaf(shid[wave][kk + 224], W2[(kk + 224) * 64 + lane], f7);
    }
    const float f = bias2[lane] + (((f0 + f1) + (f2 + f3)) + ((f4 + f5) + (f6 + f7)));
    out[(size_t)row * 64 + lane] = y + f;
}

// ---------------------------------------------------------------------------
extern "C" void kernel_launch(void* const* d_in, const int* in_sizes, int n_in,
                              void* d_out, int out_size, void* d_ws, size_t ws_size,
                              hipStream_t stream)
{
    const float* x     = (const float*)d_in[0];
    const float* Wq    = (const float*)d_in[1];
    const float* Wk    = (const float*)d_in[2];
    const float* Wv    = (const float*)d_in[3];
    const float* Wo    = (const float*)d_in[4];
    const float* bo    = (const float*)d_in[5];
    const float* W1    = (const float*)d_in[6];
    const float* bias1 = (const float*)d_in[7];
    const float* W2    = (const float*)d_in[8];
    const float* bias2 = (const float*)d_in[9];
    const float* g1    = (const float*)d_in[10];
    const float* be1   = (const float*)d_in[11];
    const float* g2    = (const float*)d_in[12];
    const float* be2   = (const float*)d_in[13];

    const size_t nBF = (size_t)32 * Tn * 16;         // 1M elements per buffer
    unsigned short* Qb = (unsigned short*)d_ws;
    unsigned short* Kb = Qb + nBF;
    unsigned short* VT = Kb + nBF;
    float* AO = (float*)(VT + nBF);                  // 4 MB, (B,T,C) f32

    k_ln_qkv<<<dim3((Bn * Tn) / 4), dim3(256), 0, stream>>>(x, Wq, Wk, Wv, g1, be1, Qb, Kb, VT);
    k_attn<<<dim3(32 * 32), dim3(256), 0, stream>>>(Qb, Kb, VT, AO);
    k_proj_mlp<<<dim3((Bn * Tn) / 4), dim3(256), 0, stream>>>(
        x, AO, Wo, bo, g2, be2, W1, bias1, W2, bias2, (float*)d_out);
}

// Round 5
// 76.680 us; speedup vs baseline: 5.7745x; 1.8155x over previous
//
#include <hip/hip_runtime.h>

// Problem constants (B=8, T=2048, C=64, H=4, d=16)
constexpr int Bn = 8, Tn = 2048;

typedef __bf16 bf16x8 __attribute__((ext_vector_type(8)));
typedef float  f32x16 __attribute__((ext_vector_type(16)));
typedef unsigned short ushort_t;

__device__ __forceinline__ unsigned short f2bf(float f) {
    __bf16 h = (__bf16)f;
    return __builtin_bit_cast(unsigned short, h);
}

// crow-order (C/D register order) -> contiguous-k B-operand fragment.
// Own 8 values are the 16-k window's channels {4hi+0..3, 8+4hi+0..3}; the
// mismatched quad is exchanged across lane<32/lane>=32. (HW-validated in attn.)
__device__ __forceinline__ bf16x8 xch_frag(
    float a0, float a1, float a2, float a3,
    float a4, float a5, float a6, float a7, int hi)
{
    const float s0 = hi ? a0 : a4, s1 = hi ? a1 : a5;
    const float s2 = hi ? a2 : a6, s3 = hi ? a3 : a7;
    const float r0 = __shfl_xor(s0, 32), r1 = __shfl_xor(s1, 32);
    const float r2 = __shfl_xor(s2, 32), r3 = __shfl_xor(s3, 32);
    bf16x8 f;
    f[0] = (__bf16)(hi ? r0 : a0); f[1] = (__bf16)(hi ? r1 : a1);
    f[2] = (__bf16)(hi ? r2 : a2); f[3] = (__bf16)(hi ? r3 : a3);
    f[4] = (__bf16)(hi ? a4 : r0); f[5] = (__bf16)(hi ? a5 : r1);
    f[6] = (__bf16)(hi ? a6 : r2); f[7] = (__bf16)(hi ? a7 : r3);
    return f;
}

// ---------------------------------------------------------------------------
// Kernel P: weight prep — bf16 transposed copies of Wo, W1, W2.
// WoT[n][k]=Wo[k][n] (64x64); W1T[n][k]=W1[k][n] (256x64); W2T[n][k]=W2[k][n] (64x256).
// ---------------------------------------------------------------------------
__global__ __launch_bounds__(256) void k_prep(
    const float* __restrict__ Wo, const float* __restrict__ W1, const float* __restrict__ W2,
    ushort_t* __restrict__ WoT, ushort_t* __restrict__ W1T, ushort_t* __restrict__ W2T)
{
    const int i = blockIdx.x * 256 + threadIdx.x;
    if (i < 4096) {
        const int n = i >> 6, k = i & 63;
        WoT[i] = f2bf(Wo[k * 64 + n]);
    } else if (i < 20480) {
        const int i2 = i - 4096, n = i2 >> 6, k = i2 & 63;
        W1T[i2] = f2bf(W1[k * 256 + n]);
    } else if (i < 36864) {
        const int i2 = i - 20480, n = i2 >> 8, k = i2 & 255;
        W2T[i2] = f2bf(W2[k * 64 + n]);
    }
}

// ---------------------------------------------------------------------------
// Kernel A: LayerNorm1 + QKV projection (unchanged from R4).
// ---------------------------------------------------------------------------
__global__ __launch_bounds__(256) void k_ln_qkv(
    const float* __restrict__ x,
    const float* __restrict__ Wq, const float* __restrict__ Wk, const float* __restrict__ Wv,
    const float* __restrict__ g1, const float* __restrict__ b1,
    ushort_t* __restrict__ Qb, ushort_t* __restrict__ Kb, ushort_t* __restrict__ VT)
{
    const int wave = threadIdx.x >> 6, lane = threadIdx.x & 63;
    const int row  = blockIdx.x * 4 + wave;

    float xv = x[(size_t)row * 64 + lane];
    float s = xv, sq = xv * xv;
    #pragma unroll
    for (int off = 32; off; off >>= 1) {
        s  += __shfl_xor(s,  off);
        sq += __shfl_xor(sq, off);
    }
    const float mu  = s * (1.f / 64.f);
    const float var = sq * (1.f / 64.f) - mu * mu;
    const float rs  = rsqrtf(var + 1e-5f);
    const float hn  = (xv - mu) * rs * g1[lane] + b1[lane];

    __shared__ float sh[4][64];
    sh[wave][lane] = hn;
    __syncthreads();

    const int h = lane >> 4, d = lane & 15;
    const float* wq = Wq + h * (64 * 16) + d;
    const float* wk = Wk + h * (64 * 16) + d;
    const float* wv = Wv + h * (64 * 16) + d;
    float qa = 0.f, ka = 0.f, va = 0.f, qb2 = 0.f, kb2 = 0.f, vb2 = 0.f;
    #pragma unroll
    for (int c = 0; c < 32; ++c) {
        const float ha = sh[wave][c], hb = sh[wave][c + 32];
        qa  = fmaf(ha, wq[c * 16], qa);
        ka  = fmaf(ha, wk[c * 16], ka);
        va  = fmaf(ha, wv[c * 16], va);
        qb2 = fmaf(hb, wq[(c + 32) * 16], qb2);
        kb2 = fmaf(hb, wk[(c + 32) * 16], kb2);
        vb2 = fmaf(hb, wv[(c + 32) * 16], vb2);
    }
    const int b = row >> 11, t = row & 2047;
    const int bh = b * 4 + h;
    Qb[((size_t)bh * Tn + t) * 16 + d] = f2bf((qa + qb2) * 0.25f);
    Kb[((size_t)bh * Tn + t) * 16 + d] = f2bf(ka + kb2);
    VT[((size_t)bh * 16 + d) * Tn + t] = f2bf(va + vb2);
}

// ---------------------------------------------------------------------------
// Kernel B: causal flash attention (R4 structure), epilogue now writes bf16 AO.
// ---------------------------------------------------------------------------
__global__ __launch_bounds__(256) void k_attn(
    const ushort_t* __restrict__ Qb, const ushort_t* __restrict__ Kb,
    const ushort_t* __restrict__ VT, ushort_t* __restrict__ AOb)
{
    const int wave = threadIdx.x >> 6, lane = threadIdx.x & 63;
    const int bh  = blockIdx.x >> 5;                 // 0..31
    const int qtA = blockIdx.x & 31;                 // 0..31
    const int w = wave;                              // key quarter
    const int hi = lane >> 5, qcol = lane & 31;
    const int b = bh >> 2, h = bh & 3;

    const ushort_t* Qbh = Qb + (size_t)bh * (Tn * 16);
    const ushort_t* Kbh = Kb + (size_t)bh * (Tn * 16);
    const ushort_t* Vbh = VT + (size_t)bh * (16 * Tn);

    __shared__ float red[4][2][64][12];              // m, l, o[8], pad

    for (int rep = 0; rep < 2; ++rep) {
        const int qt = rep ? (63 - qtA) : qtA;
        const int qg = qt * 32 + qcol;

        const bf16x8 qf = *(const bf16x8*)(Qbh + (size_t)qg * 16 + 8 * hi);

        float m = -30000.f, l = 0.f;
        f32x16 oacc = {};

        for (int kt = w; kt <= qt; kt += 4) {
            const int kbase = kt * 32;
            const bf16x8 kf = *(const bf16x8*)(Kbh + (size_t)(kbase + qcol) * 16 + 8 * hi);
            f32x16 z = {};
            f32x16 st = __builtin_amdgcn_mfma_f32_32x32x16_bf16(kf, qf, z, 0, 0, 0);

            float sv[16];
            #pragma unroll
            for (int r = 0; r < 16; ++r) sv[r] = st[r];
            if (kt == qt) {                          // diagonal: causal mask
                #pragma unroll
                for (int r = 0; r < 16; ++r) {
                    const int kr = (r & 3) + 8 * (r >> 2) + 4 * hi;
                    if (kr > qcol) sv[r] = -30000.f;
                }
            }

            float tm = sv[0];
            #pragma unroll
            for (int r = 1; r < 16; ++r) tm = fmaxf(tm, sv[r]);
            tm = fmaxf(tm, __shfl_xor(tm, 32));      // cross-half max (same q)
            const float mnew = fmaxf(m, tm);
            if (!__all(mnew <= m)) {                 // defer-max (T13)
                const float corr = __expf(m - mnew);
                m = mnew;
                l *= corr;
                #pragma unroll
                for (int r = 0; r < 8; ++r) oacc[r] *= corr;
            }

            float p[16];
            float ps = 0.f;
            #pragma unroll
            for (int r = 0; r < 16; ++r) { p[r] = __expf(sv[r] - m); ps += p[r]; }
            l += ps;

            const bf16x8 pa0 = xch_frag(p[0], p[1], p[2],  p[3],  p[4],  p[5],  p[6],  p[7],  hi);
            const bf16x8 pa1 = xch_frag(p[8], p[9], p[10], p[11], p[12], p[13], p[14], p[15], hi);

            const ushort_t* vrow = Vbh + (size_t)(lane & 15) * Tn + kbase + 8 * hi;
            const bf16x8 vf0 = *(const bf16x8*)(vrow);
            const bf16x8 vf1 = *(const bf16x8*)(vrow + 16);

            oacc = __builtin_amdgcn_mfma_f32_32x32x16_bf16(vf0, pa0, oacc, 0, 0, 0);
            oacc = __builtin_amdgcn_mfma_f32_32x32x16_bf16(vf1, pa1, oacc, 0, 0, 0);
        }

        l += __shfl_xor(l, 32);

        float* sp = &red[wave][rep][lane][0];
        sp[0] = m; sp[1] = l;
        #pragma unroll
        for (int r = 0; r < 8; ++r) sp[2 + r] = oacc[r];
    }
    __syncthreads();

    if (wave < 2) {
        const int r_m = wave;
        const float* p0 = &red[0][r_m][lane][0];
        const float* p1 = &red[1][r_m][lane][0];
        const float* p2 = &red[2][r_m][lane][0];
        const float* p3 = &red[3][r_m][lane][0];
        const float mm = fmaxf(fmaxf(p0[0], p1[0]), fmaxf(p2[0], p3[0]));
        const float c0 = __expf(p0[0] - mm), c1 = __expf(p1[0] - mm);
        const float c2 = __expf(p2[0] - mm), c3 = __expf(p3[0] - mm);
        const float lt = fmaf(p0[1], c0, fmaf(p1[1], c1, fmaf(p2[1], c2, p3[1] * c3)));
        const float inv = 1.f / lt;

        const int qt_out = r_m ? (63 - qtA) : qtA;
        const int qg2 = qt_out * 32 + qcol;

        float o[8];
        #pragma unroll
        for (int r = 0; r < 8; ++r)
            o[r] = fmaf(p0[2 + r], c0, fmaf(p1[2 + r], c1,
                   fmaf(p2[2 + r], c2, p3[2 + r] * c3))) * inv;

        ushort_t* dst = AOb + ((size_t)b * Tn + qg2) * 64 + h * 16;
        ushort4 u0, u1;
        u0.x = f2bf(o[0]); u0.y = f2bf(o[1]); u0.z = f2bf(o[2]); u0.w = f2bf(o[3]);
        u1.x = f2bf(o[4]); u1.y = f2bf(o[5]); u1.z = f2bf(o[6]); u1.w = f2bf(o[7]);
        *(ushort4*)(dst + 4 * hi)     = u0;
        *(ushort4*)(dst + 8 + 4 * hi) = u1;
    }
}

// ---------------------------------------------------------------------------
// Kernel C (rewritten): MFMA out-proj + residual + LN2 + MLP + residual.
// One wave per 32 tokens; all GEMMs transposed (lane = token column,
// crow regs = output channels). Weight fragments amortized across 32 rows.
//   Y^T  = mfma(WoT, AO)          : 2 n-tiles x 4 ksteps  =  8 mfma
//   H^T  = mfma(W1T, h)  per grp  : 8 grps x 4 ksteps     = 32 mfma
//   O^T += mfma(W2T, Hg) per grp  : 8 grps x 2x2          = 32 mfma
// ---------------------------------------------------------------------------
__global__ __launch_bounds__(64) void k_mlp(
    const float* __restrict__ x, const ushort_t* __restrict__ AOb,
    const ushort_t* __restrict__ WoT, const float* __restrict__ bo,
    const float* __restrict__ g2, const float* __restrict__ b2v,
    const ushort_t* __restrict__ W1T, const float* __restrict__ bias1,
    const ushort_t* __restrict__ W2T, const float* __restrict__ bias2,
    float* __restrict__ out)
{
    const int lane = threadIdx.x & 63;
    const int hi = lane >> 5, m31 = lane & 31;
    const size_t m = (size_t)blockIdx.x * 32 + m31;

    // ---- Wo projection: y^T[n][m]
    f32x16 y0 = {}, y1 = {};
    {
        const ushort_t* ar = AOb + m * 64 + 8 * hi;
        const ushort_t* w0 = WoT + (size_t)m31 * 64 + 8 * hi;
        const ushort_t* w1 = WoT + (size_t)(m31 + 32) * 64 + 8 * hi;
        #pragma unroll
        for (int ks = 0; ks < 4; ++ks) {
            const bf16x8 bf = *(const bf16x8*)(ar + 16 * ks);
            const bf16x8 a0 = *(const bf16x8*)(w0 + 16 * ks);
            const bf16x8 a1 = *(const bf16x8*)(w1 + 16 * ks);
            y0 = __builtin_amdgcn_mfma_f32_32x32x16_bf16(a0, bf, y0, 0, 0, 0);
            y1 = __builtin_amdgcn_mfma_f32_32x32x16_bf16(a1, bf, y1, 0, 0, 0);
        }
    }

    // ---- + x + bo  (reg r of tile t: channel n = 32t + 8*(r>>2) + 4hi + (r&3))
    #pragma unroll
    for (int q2 = 0; q2 < 4; ++q2) {
        {
            const int nb = 8 * q2 + 4 * hi;
            const float4 xq = *(const float4*)(x + m * 64 + nb);
            const float4 bq = *(const float4*)(bo + nb);
            y0[4*q2+0] += xq.x + bq.x; y0[4*q2+1] += xq.y + bq.y;
            y0[4*q2+2] += xq.z + bq.z; y0[4*q2+3] += xq.w + bq.w;
        }
        {
            const int nb = 32 + 8 * q2 + 4 * hi;
            const float4 xq = *(const float4*)(x + m * 64 + nb);
            const float4 bq = *(const float4*)(bo + nb);
            y1[4*q2+0] += xq.x + bq.x; y1[4*q2+1] += xq.y + bq.y;
            y1[4*q2+2] += xq.z + bq.z; y1[4*q2+3] += xq.w + bq.w;
        }
    }

    // ---- LN2 (token m: 32 channels in-lane + 32 in partner lane m^32)
    float s = 0.f, sq = 0.f;
    #pragma unroll
    for (int r = 0; r < 16; ++r) {
        s  += y0[r] + y1[r];
        sq += y0[r] * y0[r] + y1[r] * y1[r];
    }
    s  += __shfl_xor(s,  32);
    sq += __shfl_xor(sq, 32);
    const float mu  = s * (1.f / 64.f);
    const float var = sq * (1.f / 64.f) - mu * mu;
    const float rs  = rsqrtf(var + 1e-5f);

    float hreg[32];                                  // h channels, crow order
    #pragma unroll
    for (int q2 = 0; q2 < 4; ++q2) {
        {
            const int nb = 8 * q2 + 4 * hi;
            const float4 gq = *(const float4*)(g2 + nb);
            const float4 bq = *(const float4*)(b2v + nb);
            hreg[4*q2+0] = (y0[4*q2+0] - mu) * rs * gq.x + bq.x;
            hreg[4*q2+1] = (y0[4*q2+1] - mu) * rs * gq.y + bq.y;
            hreg[4*q2+2] = (y0[4*q2+2] - mu) * rs * gq.z + bq.z;
            hreg[4*q2+3] = (y0[4*q2+3] - mu) * rs * gq.w + bq.w;
        }
        {
            const int nb = 32 + 8 * q2 + 4 * hi;
            const float4 gq = *(const float4*)(g2 + nb);
            const float4 bq = *(const float4*)(b2v + nb);
            hreg[16+4*q2+0] = (y1[4*q2+0] - mu) * rs * gq.x + bq.x;
            hreg[16+4*q2+1] = (y1[4*q2+1] - mu) * rs * gq.y + bq.y;
            hreg[16+4*q2+2] = (y1[4*q2+2] - mu) * rs * gq.z + bq.z;
            hreg[16+4*q2+3] = (y1[4*q2+3] - mu) * rs * gq.w + bq.w;
        }
    }

    // ---- MLP: 8 hidden groups of 32
    f32x16 o0 = {}, o1 = {};
    #pragma unroll
    for (int g = 0; g < 8; ++g) {
        f32x16 hacc = {};
        #pragma unroll
        for (int ks = 0; ks < 4; ++ks) {             // fc1, k = LN channels
            const int base = 16 * (ks >> 1) + 8 * (ks & 1);
            const bf16x8 bf = xch_frag(hreg[base+0], hreg[base+1], hreg[base+2], hreg[base+3],
                                       hreg[base+4], hreg[base+5], hreg[base+6], hreg[base+7], hi);
            const bf16x8 a = *(const bf16x8*)(W1T + (size_t)(32 * g + m31) * 64 + 16 * ks + 8 * hi);
            hacc = __builtin_amdgcn_mfma_f32_32x32x16_bf16(a, bf, hacc, 0, 0, 0);
        }
        float hv[16];                                // relu(h + b1), crow order
        #pragma unroll
        for (int q2 = 0; q2 < 4; ++q2) {
            const int nb = 32 * g + 8 * q2 + 4 * hi;
            const float4 bq = *(const float4*)(bias1 + nb);
            hv[4*q2+0] = fmaxf(hacc[4*q2+0] + bq.x, 0.f);
            hv[4*q2+1] = fmaxf(hacc[4*q2+1] + bq.y, 0.f);
            hv[4*q2+2] = fmaxf(hacc[4*q2+2] + bq.z, 0.f);
            hv[4*q2+3] = fmaxf(hacc[4*q2+3] + bq.w, 0.f);
        }
        #pragma unroll
        for (int w2 = 0; w2 < 2; ++w2) {             // fc2, k = hidden units
            const int base = 8 * w2;
            const bf16x8 bf = xch_frag(hv[base+0], hv[base+1], hv[base+2], hv[base+3],
                                       hv[base+4], hv[base+5], hv[base+6], hv[base+7], hi);
            const bf16x8 a0 = *(const bf16x8*)(W2T + (size_t)m31 * 256 + 32 * g + 16 * w2 + 8 * hi);
            const bf16x8 a1 = *(const bf16x8*)(W2T + (size_t)(m31 + 32) * 256 + 32 * g + 16 * w2 + 8 * hi);
            o0 = __builtin_amdgcn_mfma_f32_32x32x16_bf16(a0, bf, o0, 0, 0, 0);
            o1 = __builtin_amdgcn_mfma_f32_32x32x16_bf16(a1, bf, o1, 0, 0, 0);
        }
    }

    // ---- epilogue: out = y + mlp + bias2
    #pragma unroll
    for (int q2 = 0; q2 < 4; ++q2) {
        {
            const int nb = 8 * q2 + 4 * hi;
            const float4 bq = *(const float4*)(bias2 + nb);
            float4 r;
            r.x = y0[4*q2+0] + o0[4*q2+0] + bq.x;
            r.y = y0[4*q2+1] + o0[4*q2+1] + bq.y;
            r.z = y0[4*q2+2] + o0[4*q2+2] + bq.z;
            r.w = y0[4*q2+3] + o0[4*q2+3] + bq.w;
            *(float4*)(out + m * 64 + nb) = r;
        }
        {
            const int nb = 32 + 8 * q2 + 4 * hi;
            const float4 bq = *(const float4*)(bias2 + nb);
            float4 r;
            r.x = y1[4*q2+0] + o1[4*q2+0] + bq.x;
            r.y = y1[4*q2+1] + o1[4*q2+1] + bq.y;
            r.z = y1[4*q2+2] + o1[4*q2+2] + bq.z;
            r.w = y1[4*q2+3] + o1[4*q2+3] + bq.w;
            *(float4*)(out + m * 64 + nb) = r;
        }
    }
}

// ---------------------------------------------------------------------------
extern "C" void kernel_launch(void* const* d_in, const int* in_sizes, int n_in,
                              void* d_out, int out_size, void* d_ws, size_t ws_size,
                              hipStream_t stream)
{
    const float* x     = (const float*)d_in[0];
    const float* Wq    = (const float*)d_in[1];
    const float* Wk    = (const float*)d_in[2];
    const float* Wv    = (const float*)d_in[3];
    const float* Wo    = (const float*)d_in[4];
    const float* bo    = (const float*)d_in[5];
    const float* W1    = (const float*)d_in[6];
    const float* bias1 = (const float*)d_in[7];
    const float* W2    = (const float*)d_in[8];
    const float* bias2 = (const float*)d_in[9];
    const float* g1    = (const float*)d_in[10];
    const float* be1   = (const float*)d_in[11];
    const float* g2    = (const float*)d_in[12];
    const float* be2   = (const float*)d_in[13];

    const size_t nBF = (size_t)32 * Tn * 16;         // 1M elements per buffer
    ushort_t* Qb  = (ushort_t*)d_ws;
    ushort_t* Kb  = Qb + nBF;
    ushort_t* VT  = Kb + nBF;
    ushort_t* AOb = VT + nBF;                        // bf16 attn out (B,T,C)
    ushort_t* WoT = AOb + nBF;                       // 4096
    ushort_t* W1T = WoT + 4096;                      // 16384
    ushort_t* W2T = W1T + 16384;                     // 16384

    k_prep<<<dim3(144), dim3(256), 0, stream>>>(Wo, W1, W2, WoT, W1T, W2T);
    k_ln_qkv<<<dim3((Bn * Tn) / 4), dim3(256), 0, stream>>>(x, Wq, Wk, Wv, g1, be1, Qb, Kb, VT);
    k_attn<<<dim3(32 * 32), dim3(256), 0, stream>>>(Qb, Kb, VT, AOb);
    k_mlp<<<dim3((Bn * Tn) / 32), dim3(64), 0, stream>>>(
        x, AOb, WoT, bo, g2, be2, W1T, bias1, W2T, bias2, (float*)d_out);
}

// Round 6
// 74.473 us; speedup vs baseline: 5.9457x; 1.0296x over previous
//
#include <hip/hip_runtime.h>

// Problem constants (B=8, T=2048, C=64, H=4, d=16)
constexpr int Bn = 8, Tn = 2048;

typedef __bf16 bf16x8 __attribute__((ext_vector_type(8)));
typedef float  f32x16 __attribute__((ext_vector_type(16)));
typedef unsigned short ushort_t;

__device__ __forceinline__ unsigned short f2bf(float f) {
    __bf16 h = (__bf16)f;
    return __builtin_bit_cast(unsigned short, h);
}

__device__ __forceinline__ float fast_exp2(float x) {
    float r;
    asm("v_exp_f32 %0, %1" : "=v"(r) : "v"(x));
    return r;
}

__device__ __forceinline__ unsigned cvt_pk_bf16(float lo, float hi_) {
    unsigned r;
    asm("v_cvt_pk_bf16_f32 %0, %1, %2" : "=v"(r) : "v"(lo), "v"(hi_));
    return r;
}

// crow-order (C/D register order) -> contiguous-k B-operand fragment (f32 path,
// used by k_mlp; HW-validated).
__device__ __forceinline__ bf16x8 xch_frag(
    float a0, float a1, float a2, float a3,
    float a4, float a5, float a6, float a7, int hi)
{
    const float s0 = hi ? a0 : a4, s1 = hi ? a1 : a5;
    const float s2 = hi ? a2 : a6, s3 = hi ? a3 : a7;
    const float r0 = __shfl_xor(s0, 32), r1 = __shfl_xor(s1, 32);
    const float r2 = __shfl_xor(s2, 32), r3 = __shfl_xor(s3, 32);
    bf16x8 f;
    f[0] = (__bf16)(hi ? r0 : a0); f[1] = (__bf16)(hi ? r1 : a1);
    f[2] = (__bf16)(hi ? r2 : a2); f[3] = (__bf16)(hi ? r3 : a3);
    f[4] = (__bf16)(hi ? a4 : r0); f[5] = (__bf16)(hi ? a5 : r1);
    f[6] = (__bf16)(hi ? a6 : r2); f[7] = (__bf16)(hi ? a7 : r3);
    return f;
}

// ---------------------------------------------------------------------------
// Kernel P: weight prep (bf16 transposed Wo/W1/W2) + ones-row of VT.
// VT layout: [bh][32][Tn]; rows 0-15 = V^T, row 16 = 1.0 (l-accumulator row),
// rows 17-31 never written (garbage values land in unread acc regs).
// ---------------------------------------------------------------------------
__global__ __launch_bounds__(256) void k_prep(
    const float* __restrict__ Wo, const float* __restrict__ W1, const float* __restrict__ W2,
    ushort_t* __restrict__ WoT, ushort_t* __restrict__ W1T, ushort_t* __restrict__ W2T,
    ushort_t* __restrict__ VT)
{
    const int i = blockIdx.x * 256 + threadIdx.x;
    if (i < 4096) {
        const int n = i >> 6, k = i & 63;
        WoT[i] = f2bf(Wo[k * 64 + n]);
    } else if (i < 20480) {
        const int i2 = i - 4096, n = i2 >> 6, k = i2 & 63;
        W1T[i2] = f2bf(W1[k * 256 + n]);
    } else if (i < 36864) {
        const int i2 = i - 20480, n = i2 >> 8, k = i2 & 255;
        W2T[i2] = f2bf(W2[k * 64 + n]);
    } else if (i < 102400) {
        const int i2 = i - 36864;                    // 0..65535
        const int bh = i2 >> 11, t = i2 & 2047;
        VT[((size_t)bh * 32 + 16) * Tn + t] = 0x3F80;  // bf16 1.0
    }
}

// ---------------------------------------------------------------------------
// Kernel A: LayerNorm1 + QKV projection.
// Q pre-scaled by 0.25*log2(e) (exp2-space softmax). VT stride = 32 rows/bh.
// ---------------------------------------------------------------------------
__global__ __launch_bounds__(256) void k_ln_qkv(
    const float* __restrict__ x,
    const float* __restrict__ Wq, const float* __restrict__ Wk, const float* __restrict__ Wv,
    const float* __restrict__ g1, const float* __restrict__ b1,
    ushort_t* __restrict__ Qb, ushort_t* __restrict__ Kb, ushort_t* __restrict__ VT)
{
    const int wave = threadIdx.x >> 6, lane = threadIdx.x & 63;
    const int row  = blockIdx.x * 4 + wave;

    float xv = x[(size_t)row * 64 + lane];
    float s = xv, sq = xv * xv;
    #pragma unroll
    for (int off = 32; off; off >>= 1) {
        s  += __shfl_xor(s,  off);
        sq += __shfl_xor(sq, off);
    }
    const float mu  = s * (1.f / 64.f);
    const float var = sq * (1.f / 64.f) - mu * mu;
    const float rs  = rsqrtf(var + 1e-5f);
    const float hn  = (xv - mu) * rs * g1[lane] + b1[lane];

    __shared__ float sh[4][64];
    sh[wave][lane] = hn;
    __syncthreads();

    const int h = lane >> 4, d = lane & 15;
    const float* wq = Wq + h * (64 * 16) + d;
    const float* wk = Wk + h * (64 * 16) + d;
    const float* wv = Wv + h * (64 * 16) + d;
    float qa = 0.f, ka = 0.f, va = 0.f, qb2 = 0.f, kb2 = 0.f, vb2 = 0.f;
    #pragma unroll
    for (int c = 0; c < 32; ++c) {
        const float ha = sh[wave][c], hb = sh[wave][c + 32];
        qa  = fmaf(ha, wq[c * 16], qa);
        ka  = fmaf(ha, wk[c * 16], ka);
        va  = fmaf(ha, wv[c * 16], va);
        qb2 = fmaf(hb, wq[(c + 32) * 16], qb2);
        kb2 = fmaf(hb, wk[(c + 32) * 16], kb2);
        vb2 = fmaf(hb, wv[(c + 32) * 16], vb2);
    }
    const int b = row >> 11, t = row & 2047;
    const int bh = b * 4 + h;
    Qb[((size_t)bh * Tn + t) * 16 + d] = f2bf((qa + qb2) * 0.360673760222f);  // 0.25*log2e
    Kb[((size_t)bh * Tn + t) * 16 + d] = f2bf(ka + kb2);
    VT[((size_t)bh * 32 + d) * Tn + t] = f2bf(va + vb2);
}

// ---------------------------------------------------------------------------
// Kernel B: causal flash attention, exp2-space, slim inner loop.
//  - QK^T C-init = -m  => st = s2 - m directly (no per-score subtract)
//  - rescale check: __all(tm <= 0) (T13 defer-max; m init 12 => never fires
//    for this data scale, correct for any input)
//  - l = Sum(p) accumulated FOR FREE by the PV mfma via VT ones-row (row 16
//    -> oacc[8] at hi=0)
//  - P fragment: cvt_pk_bf16 packs + 4 packed shfl_xor(32) (T12)
//  - K/V software prefetch (depth 1, clamped)
// ---------------------------------------------------------------------------
__global__ __launch_bounds__(256) void k_attn(
    const ushort_t* __restrict__ Qb, const ushort_t* __restrict__ Kb,
    const ushort_t* __restrict__ VT, ushort_t* __restrict__ AOb)
{
    const int wave = threadIdx.x >> 6, lane = threadIdx.x & 63;
    const int bh  = blockIdx.x >> 5;                 // 0..31
    const int qtA = blockIdx.x & 31;                 // 0..31
    const int w = wave;                              // key quarter
    const int hi = lane >> 5, qcol = lane & 31;
    const int b = bh >> 2, h = bh & 3;

    const ushort_t* Qbh = Qb + (size_t)bh * (Tn * 16);
    const ushort_t* kaddr = Kb + (size_t)bh * (Tn * 16) + (size_t)qcol * 16 + 8 * hi;
    const ushort_t* vaddr = VT + (size_t)bh * (32 * Tn) + (size_t)(lane & 31) * Tn + 8 * hi;

    __shared__ float red[4][2][64][12];              // m, l, o[8], pad

    for (int rep = 0; rep < 2; ++rep) {
        const int qt = rep ? (63 - qtA) : qtA;
        const int qg = qt * 32 + qcol;

        const bf16x8 qf = *(const bf16x8*)(Qbh + (size_t)qg * 16 + 8 * hi);

        float m = 12.0f;                             // log2-space headroom
        f32x16 oacc = {};

        if (w <= qt) {
            bf16x8 kf  = *(const bf16x8*)(kaddr + (size_t)w * 512);
            bf16x8 vf0 = *(const bf16x8*)(vaddr + w * 32);
            bf16x8 vf1 = *(const bf16x8*)(vaddr + w * 32 + 16);

            for (int kt = w; kt <= qt; kt += 4) {
                const int ktn = (kt + 4 <= qt) ? (kt + 4) : qt;   // clamped prefetch
                bf16x8 kfn  = *(const bf16x8*)(kaddr + (size_t)ktn * 512);
                bf16x8 vf0n = *(const bf16x8*)(vaddr + ktn * 32);
                bf16x8 vf1n = *(const bf16x8*)(vaddr + ktn * 32 + 16);

                f32x16 cinit;
                #pragma unroll
                for (int r = 0; r < 16; ++r) cinit[r] = -m;
                f32x16 st = __builtin_amdgcn_mfma_f32_32x32x16_bf16(kf, qf, cinit, 0, 0, 0);

                if (kt == qt) {                      // diagonal: causal mask
                    #pragma unroll
                    for (int r = 0; r < 16; ++r) {
                        const int kr = (r & 3) + 8 * (r >> 2) + 4 * hi;
                        if (kr > qcol) st[r] = -30000.f;
                    }
                }

                // any score above current max? (st is already s2 - m)
                float tm = fmaxf(fmaxf(fmaxf(st[0], st[1]),  fmaxf(st[2],  st[3])),
                                 fmaxf(fmaxf(st[4], st[5]),  fmaxf(st[6],  st[7])));
                tm = fmaxf(tm,
                     fmaxf(fmaxf(fmaxf(st[8], st[9]),  fmaxf(st[10], st[11])),
                           fmaxf(fmaxf(st[12], st[13]), fmaxf(st[14], st[15]))));
                if (!__all(tm <= 0.f)) {             // defer-max: rare path
                    float tm2 = fmaxf(tm, __shfl_xor(tm, 32));
                    tm2 = fmaxf(tm2, 0.f);
                    const float corr = fast_exp2(-tm2);
                    m += tm2;
                    #pragma unroll
                    for (int r = 0; r < 9; ++r) oacc[r] *= corr;   // incl. l at [8]
                    #pragma unroll
                    for (int r = 0; r < 16; ++r) st[r] -= tm2;
                }

                float p[16];
                #pragma unroll
                for (int r = 0; r < 16; ++r) p[r] = fast_exp2(st[r]);

                // pack to bf16 pairs, then exchange packed words across halves
                const unsigned w0 = cvt_pk_bf16(p[0],  p[1]),  w1 = cvt_pk_bf16(p[2],  p[3]);
                const unsigned w2 = cvt_pk_bf16(p[4],  p[5]),  w3 = cvt_pk_bf16(p[6],  p[7]);
                const unsigned w4 = cvt_pk_bf16(p[8],  p[9]),  w5 = cvt_pk_bf16(p[10], p[11]);
                const unsigned w6 = cvt_pk_bf16(p[12], p[13]), w7 = cvt_pk_bf16(p[14], p[15]);
                const unsigned r0 = __shfl_xor(hi ? w0 : w2, 32);
                const unsigned r1 = __shfl_xor(hi ? w1 : w3, 32);
                const unsigned r2 = __shfl_xor(hi ? w4 : w6, 32);
                const unsigned r3 = __shfl_xor(hi ? w5 : w7, 32);

                union { unsigned u[4]; bf16x8 v; } pa0, pa1;
                pa0.u[0] = hi ? r0 : w0;  pa0.u[1] = hi ? r1 : w1;
                pa0.u[2] = hi ? w2 : r0;  pa0.u[3] = hi ? w3 : r1;
                pa1.u[0] = hi ? r2 : w4;  pa1.u[1] = hi ? r3 : w5;
                pa1.u[2] = hi ? w6 : r2;  pa1.u[3] = hi ? w7 : r3;

                oacc = __builtin_amdgcn_mfma_f32_32x32x16_bf16(vf0, pa0.v, oacc, 0, 0, 0);
                oacc = __builtin_amdgcn_mfma_f32_32x32x16_bf16(vf1, pa1.v, oacc, 0, 0, 0);

                kf = kfn; vf0 = vf0n; vf1 = vf1n;
            }
        }

        // l lives in oacc[8] (ones-row output) on hi=0 lanes only
        const float lo_ = __shfl_xor(oacc[8], 32);
        const float l = hi ? lo_ : oacc[8];

        float* sp = &red[wave][rep][lane][0];
        sp[0] = m; sp[1] = l;
        #pragma unroll
        for (int r = 0; r < 8; ++r) sp[2 + r] = oacc[r];
    }
    __syncthreads();

    if (wave < 2) {
        const int r_m = wave;
        const float* p0 = &red[0][r_m][lane][0];
        const float* p1 = &red[1][r_m][lane][0];
        const float* p2 = &red[2][r_m][lane][0];
        const float* p3 = &red[3][r_m][lane][0];
        const float mm = fmaxf(fmaxf(p0[0], p1[0]), fmaxf(p2[0], p3[0]));
        const float c0 = fast_exp2(p0[0] - mm), c1 = fast_exp2(p1[0] - mm);
        const float c2 = fast_exp2(p2[0] - mm), c3 = fast_exp2(p3[0] - mm);
        const float lt = fmaf(p0[1], c0, fmaf(p1[1], c1, fmaf(p2[1], c2, p3[1] * c3)));
        const float inv = 1.f / lt;

        const int qt_out = r_m ? (63 - qtA) : qtA;
        const int qg2 = qt_out * 32 + qcol;

        float o[8];
        #pragma unroll
        for (int r = 0; r < 8; ++r)
            o[r] = fmaf(p0[2 + r], c0, fmaf(p1[2 + r], c1,
                   fmaf(p2[2 + r], c2, p3[2 + r] * c3))) * inv;

        ushort_t* dst = AOb + ((size_t)b * Tn + qg2) * 64 + h * 16;
        ushort4 u0, u1;
        u0.x = f2bf(o[0]); u0.y = f2bf(o[1]); u0.z = f2bf(o[2]); u0.w = f2bf(o[3]);
        u1.x = f2bf(o[4]); u1.y = f2bf(o[5]); u1.z = f2bf(o[6]); u1.w = f2bf(o[7]);
        *(ushort4*)(dst + 4 * hi)     = u0;
        *(ushort4*)(dst + 8 + 4 * hi) = u1;
    }
}

// ---------------------------------------------------------------------------
// Kernel C: MFMA out-proj + residual + LN2 + MLP + residual (unchanged R5).
// ---------------------------------------------------------------------------
__global__ __launch_bounds__(64) void k_mlp(
    const float* __restrict__ x, const ushort_t* __restrict__ AOb,
    const ushort_t* __restrict__ WoT, const float* __restrict__ bo,
    const float* __restrict__ g2, const float* __restrict__ b2v,
    const ushort_t* __restrict__ W1T, const float* __restrict__ bias1,
    const ushort_t* __restrict__ W2T, const float* __restrict__ bias2,
    float* __restrict__ out)
{
    const int lane = threadIdx.x & 63;
    const int hi = lane >> 5, m31 = lane & 31;
    const size_t m = (size_t)blockIdx.x * 32 + m31;

    f32x16 y0 = {}, y1 = {};
    {
        const ushort_t* ar = AOb + m * 64 + 8 * hi;
        const ushort_t* w0 = WoT + (size_t)m31 * 64 + 8 * hi;
        const ushort_t* w1 = WoT + (size_t)(m31 + 32) * 64 + 8 * hi;
        #pragma unroll
        for (int ks = 0; ks < 4; ++ks) {
            const bf16x8 bf = *(const bf16x8*)(ar + 16 * ks);
            const bf16x8 a0 = *(const bf16x8*)(w0 + 16 * ks);
            const bf16x8 a1 = *(const bf16x8*)(w1 + 16 * ks);
            y0 = __builtin_amdgcn_mfma_f32_32x32x16_bf16(a0, bf, y0, 0, 0, 0);
            y1 = __builtin_amdgcn_mfma_f32_32x32x16_bf16(a1, bf, y1, 0, 0, 0);
        }
    }

    #pragma unroll
    for (int q2 = 0; q2 < 4; ++q2) {
        {
            const int nb = 8 * q2 + 4 * hi;
            const float4 xq = *(const float4*)(x + m * 64 + nb);
            const float4 bq = *(const float4*)(bo + nb);
            y0[4*q2+0] += xq.x + bq.x; y0[4*q2+1] += xq.y + bq.y;
            y0[4*q2+2] += xq.z + bq.z; y0[4*q2+3] += xq.w + bq.w;
        }
        {
            const int nb = 32 + 8 * q2 + 4 * hi;
            const float4 xq = *(const float4*)(x + m * 64 + nb);
            const float4 bq = *(const float4*)(bo + nb);
            y1[4*q2+0] += xq.x + bq.x; y1[4*q2+1] += xq.y + bq.y;
            y1[4*q2+2] += xq.z + bq.z; y1[4*q2+3] += xq.w + bq.w;
        }
    }

    float s = 0.f, sq = 0.f;
    #pragma unroll
    for (int r = 0; r < 16; ++r) {
        s  += y0[r] + y1[r];
        sq += y0[r] * y0[r] + y1[r] * y1[r];
    }
    s  += __shfl_xor(s,  32);
    sq += __shfl_xor(sq, 32);
    const float mu  = s * (1.f / 64.f);
    const float var = sq * (1.f / 64.f) - mu * mu;
    const float rs  = rsqrtf(var + 1e-5f);

    float hreg[32];
    #pragma unroll
    for (int q2 = 0; q2 < 4; ++q2) {
        {
            const int nb = 8 * q2 + 4 * hi;
            const float4 gq = *(const float4*)(g2 + nb);
            const float4 bq = *(const float4*)(b2v + nb);
            hreg[4*q2+0] = (y0[4*q2+0] - mu) * rs * gq.x + bq.x;
            hreg[4*q2+1] = (y0[4*q2+1] - mu) * rs * gq.y + bq.y;
            hreg[4*q2+2] = (y0[4*q2+2] - mu) * rs * gq.z + bq.z;
            hreg[4*q2+3] = (y0[4*q2+3] - mu) * rs * gq.w + bq.w;
        }
        {
            const int nb = 32 + 8 * q2 + 4 * hi;
            const float4 gq = *(const float4*)(g2 + nb);
            const float4 bq = *(const float4*)(b2v + nb);
            hreg[16+4*q2+0] = (y1[4*q2+0] - mu) * rs * gq.x + bq.x;
            hreg[16+4*q2+1] = (y1[4*q2+1] - mu) * rs * gq.y + bq.y;
            hreg[16+4*q2+2] = (y1[4*q2+2] - mu) * rs * gq.z + bq.z;
            hreg[16+4*q2+3] = (y1[4*q2+3] - mu) * rs * gq.w + bq.w;
        }
    }

    f32x16 o0 = {}, o1 = {};
    #pragma unroll
    for (int g = 0; g < 8; ++g) {
        f32x16 hacc = {};
        #pragma unroll
        for (int ks = 0; ks < 4; ++ks) {
            const int base = 16 * (ks >> 1) + 8 * (ks & 1);
            const bf16x8 bf = xch_frag(hreg[base+0], hreg[base+1], hreg[base+2], hreg[base+3],
                                       hreg[base+4], hreg[base+5], hreg[base+6], hreg[base+7], hi);
            const bf16x8 a = *(const bf16x8*)(W1T + (size_t)(32 * g + m31) * 64 + 16 * ks + 8 * hi);
            hacc = __builtin_amdgcn_mfma_f32_32x32x16_bf16(a, bf, hacc, 0, 0, 0);
        }
        float hv[16];
        #pragma unroll
        for (int q2 = 0; q2 < 4; ++q2) {
            const int nb = 32 * g + 8 * q2 + 4 * hi;
            const float4 bq = *(const float4*)(bias1 + nb);
            hv[4*q2+0] = fmaxf(hacc[4*q2+0] + bq.x, 0.f);
            hv[4*q2+1] = fmaxf(hacc[4*q2+1] + bq.y, 0.f);
            hv[4*q2+2] = fmaxf(hacc[4*q2+2] + bq.z, 0.f);
            hv[4*q2+3] = fmaxf(hacc[4*q2+3] + bq.w, 0.f);
        }
        #pragma unroll
        for (int w2 = 0; w2 < 2; ++w2) {
            const int base = 8 * w2;
            const bf16x8 bf = xch_frag(hv[base+0], hv[base+1], hv[base+2], hv[base+3],
                                       hv[base+4], hv[base+5], hv[base+6], hv[base+7], hi);
            const bf16x8 a0 = *(const bf16x8*)(W2T + (size_t)m31 * 256 + 32 * g + 16 * w2 + 8 * hi);
            const bf16x8 a1 = *(const bf16x8*)(W2T + (size_t)(m31 + 32) * 256 + 32 * g + 16 * w2 + 8 * hi);
            o0 = __builtin_amdgcn_mfma_f32_32x32x16_bf16(a0, bf, o0, 0, 0, 0);
            o1 = __builtin_amdgcn_mfma_f32_32x32x16_bf16(a1, bf, o1, 0, 0, 0);
        }
    }

    #pragma unroll
    for (int q2 = 0; q2 < 4; ++q2) {
        {
            const int nb = 8 * q2 + 4 * hi;
            const float4 bq = *(const float4*)(bias2 + nb);
            float4 r;
            r.x = y0[4*q2+0] + o0[4*q2+0] + bq.x;
            r.y = y0[4*q2+1] + o0[4*q2+1] + bq.y;
            r.z = y0[4*q2+2] + o0[4*q2+2] + bq.z;
            r.w = y0[4*q2+3] + o0[4*q2+3] + bq.w;
            *(float4*)(out + m * 64 + nb) = r;
        }
        {
            const int nb = 32 + 8 * q2 + 4 * hi;
            const float4 bq = *(const float4*)(bias2 + nb);
            float4 r;
            r.x = y1[4*q2+0] + o1[4*q2+0] + bq.x;
            r.y = y1[4*q2+1] + o1[4*q2+1] + bq.y;
            r.z = y1[4*q2+2] + o1[4*q2+2] + bq.z;
            r.w = y1[4*q2+3] + o1[4*q2+3] + bq.w;
            *(float4*)(out + m * 64 + nb) = r;
        }
    }
}

// ---------------------------------------------------------------------------
extern "C" void kernel_launch(void* const* d_in, const int* in_sizes, int n_in,
                              void* d_out, int out_size, void* d_ws, size_t ws_size,
                              hipStream_t stream)
{
    const float* x     = (const float*)d_in[0];
    const float* Wq    = (const float*)d_in[1];
    const float* Wk    = (const float*)d_in[2];
    const float* Wv    = (const float*)d_in[3];
    const float* Wo    = (const float*)d_in[4];
    const float* bo    = (const float*)d_in[5];
    const float* W1    = (const float*)d_in[6];
    const float* bias1 = (const float*)d_in[7];
    const float* W2    = (const float*)d_in[8];
    const float* bias2 = (const float*)d_in[9];
    const float* g1    = (const float*)d_in[10];
    const float* be1   = (const float*)d_in[11];
    const float* g2    = (const float*)d_in[12];
    const float* be2   = (const float*)d_in[13];

    const size_t nBF = (size_t)32 * Tn * 16;         // 1M elements
    ushort_t* Qb  = (ushort_t*)d_ws;
    ushort_t* Kb  = Qb + nBF;
    ushort_t* VT  = Kb + nBF;                        // [32][32][Tn] = 2M elements
    ushort_t* AOb = VT + 2 * nBF;
    ushort_t* WoT = AOb + nBF;                       // 4096
    ushort_t* W1T = WoT + 4096;                      // 16384
    ushort_t* W2T = W1T + 16384;                     // 16384

    k_prep<<<dim3(400), dim3(256), 0, stream>>>(Wo, W1, W2, WoT, W1T, W2T, VT);
    k_ln_qkv<<<dim3((Bn * Tn) / 4), dim3(256), 0, stream>>>(x, Wq, Wk, Wv, g1, be1, Qb, Kb, VT);
    k_attn<<<dim3(32 * 32), dim3(256), 0, stream>>>(Qb, Kb, VT, AOb);
    k_mlp<<<dim3((Bn * Tn) / 32), dim3(64), 0, stream>>>(
        x, AOb, WoT, bo, g2, be2, W1T, bias1, W2T, bias2, (float*)d_out);
}